// Round 6
// baseline (832.016 us; speedup 1.0000x reference)
//
#include <hip/hip_runtime.h>
#include <math.h>

#define N_PRED   2000000
#define N_OBS    1000000
#define RASU     200000
#define N_IMAGES 2000
#define HMAX     60
#define GRID_    121
#define NGRID3   1771561      // 121^3
#define NPAIRS   885781       // (NGRID3+1)/2
#define MC       32
#define NPART    64
#define LOG2PI_D 1.8378770664093453
#define PREP_PAD 40

// Clang-native vector types: __builtin_nontemporal_load/store require these
typedef float f4 __attribute__((ext_vector_type(4)));
typedef float f2 __attribute__((ext_vector_type(2)));
typedef int   i2 __attribute__((ext_vector_type(2)));

#define NTL(p) __builtin_nontemporal_load(p)

// ---- Kernel A0: repack asu into packed-lo16 u32 + 2-bit hi words; zero partial+accums
__global__ __launch_bounds__(256)
void repack_kernel(const int* __restrict__ asu, unsigned int* __restrict__ lo16w,
                   unsigned int* __restrict__ hi2, f4* __restrict__ zero_base,
                   int zero_count)
{
    __shared__ unsigned int hbits[256];
    int j = blockIdx.x * 256 + threadIdx.x;   // pair index (entries 2j, 2j+1)
    unsigned int myh = 0;
    if (j < NPAIRS) {
        int i0 = 2 * j;
        i2 a;
        if (i0 + 1 < NGRID3) a = *(const i2*)(asu + i0);
        else { a.x = asu[i0]; a.y = 0; }
        lo16w[j] = ((unsigned int)a.x & 0xFFFFu) | (((unsigned int)a.y & 0xFFFFu) << 16);
        myh = (((unsigned int)a.x >> 16) & 3u) | ((((unsigned int)a.y >> 16) & 3u) << 2);
    }
    hbits[threadIdx.x] = myh;
    __syncthreads();
    if ((threadIdx.x & 7) == 0 && j < NPAIRS) {
        unsigned int wbits = 0;
#pragma unroll
        for (int k = 0; k < 8; k++) wbits |= hbits[threadIdx.x + k] << (4 * k);
        hi2[j >> 3] = wbits;
    }
    // grid-stride zero of partial bins + accums (16B chunks)
    f4 zero = {0.f, 0.f, 0.f, 0.f};
    for (int k = j; k < zero_count; k += gridDim.x * 256) zero_base[k] = zero;
}

// ---- Kernel A: softplus; ZS[r][mc] = exp(w0*ql+w1*qs) * (ql + qs*eps[mc][r]); KL ----
__global__ __launch_bounds__(256)
void prep_kernel(const float* __restrict__ qloc, const float* __restrict__ qraw,
                 const float* __restrict__ eps, const float* __restrict__ sw,
                 float* __restrict__ Qs, float* __restrict__ ZS,
                 double* __restrict__ accums, int useZ)
{
    __shared__ float lds[256 * PREP_PAD];
    int t = threadIdx.x;
    int base = blockIdx.x * 256;
    int r = base + t;
    bool valid = (r < RASU);
    double klv = 0.0;
    float qs = 1.f, ql = 0.f, ewq = 0.f;
    if (valid) {
        float x  = qraw[r];
        float sp = (x > 0.f) ? (x + log1pf(expf(-x))) : log1pf(expf(x));
        qs = sp + 1e-6f;
        ql = qloc[r];
        Qs[r] = qs;
        ewq = expf(fmaf(sw[0], ql, sw[1] * qs));
        klv = (double)(-logf(qs) + 0.5f * (qs * qs + ql * ql) - 0.5f);
    }
#pragma unroll
    for (int off = 32; off; off >>= 1) klv += __shfl_down(klv, off);
    if ((t & 63) == 0) atomicAdd(&accums[0], klv);

    if (useZ) {
        // load phase: 32 coalesced column reads, scale, into LDS row t
#pragma unroll 8
        for (int k = 0; k < MC; k++) {
            float v = valid ? fmaf(qs, eps[(size_t)k * RASU + r], ql) * ewq : 0.f;
            lds[t * PREP_PAD + k] = v;
        }
        __syncthreads();
        // store phase: lanes cover (row, col16B) so each wave writes 1KB contiguous
        int rr0 = t >> 3, cc = t & 7;
        f4* Zp = (f4*)ZS;
#pragma unroll
        for (int i = 0; i < 8; i++) {
            int rr  = rr0 + i * 32;
            int row = base + rr;
            const float* p = &lds[rr * PREP_PAD + cc * 4];
            f4 v = {p[0], p[1], p[2], p[3]};
            if (row < RASU) Zp[(size_t)row * 8 + cc] = v;
        }
    }
}

// ---- Kernel C: one thread per observation ------------------------------------------
template <int USEZ, int USELOHI>
__global__ __launch_bounds__(256)
void obs_kernel(const int* __restrict__ hkl, const float* __restrict__ I,
                const float* __restrict__ SigI, const int* __restrict__ image_id,
                const float* __restrict__ metadata, const int* __restrict__ asu,
                const unsigned short* __restrict__ lo16, const unsigned int* __restrict__ hi2,
                const float* __restrict__ qloc, const float* __restrict__ Qs,
                const float* __restrict__ ZS, const float* __restrict__ eps,
                const float* __restrict__ sw, const float* __restrict__ sbp,
                const float* __restrict__ ibias, double* __restrict__ partial)
{
    int o = blockIdx.x * 256 + threadIdx.x;
    if (o >= N_OBS) return;

    float w[9];
#pragma unroll
    for (int j = 0; j < 9; j++) w[j] = sw[j];
    float sb = sbp[0];

    float Iv = NTL(I + o), Sv = NTL(SigI + o);
    float inv  = 1.0f / Sv;
    float logs = logf(Sv);

    int p0 = 2 * o;
    i2 ia = NTL((const i2*)(image_id + p0));
    int img = ia.y;  // numpy last-write-wins scatter: pred 2o+1 wins

    // per-prediction base of the log-scale (op-independent); eb = exp(base)
    float eb[2];
    {
        const f2* m0 = (const f2*)(metadata + (size_t)p0 * 5);
        f2 ma = NTL(m0), mb = NTL(m0 + 1), mc_ = NTL(m0 + 2), md = NTL(m0 + 3), me = NTL(m0 + 4);
        float m[10] = {ma.x, ma.y, mb.x, mb.y, mc_.x, mc_.y, md.x, md.y, me.x, me.y};
#pragma unroll
        for (int j = 0; j < 2; j++) {
            float b = w[2] * Iv;
            b = fmaf(w[3], Sv, b);
#pragma unroll
            for (int k = 0; k < 5; k++) b = fmaf(w[4 + k], m[5 * j + k], b);
            eb[j] = expf(b + sb + ibias[j == 0 ? ia.x : ia.y]);
        }
    }

    int h[2][3];
    {
        const i2* hp = (const i2*)(hkl + (size_t)p0 * 3);
        i2 h01 = NTL(hp), h23 = NTL(hp + 1), h45 = NTL(hp + 2);
        h[0][0] = h01.x; h[0][1] = h01.y; h[0][2] = h23.x;
        h[1][0] = h23.y; h[1][1] = h45.x; h[1][2] = h45.y;
    }

    int r[3][2];
#pragma unroll
    for (int j = 0; j < 2; j++) {
        int flat[3];
        flat[0] = ((h[j][0] + HMAX) * GRID_ + (h[j][1] + HMAX)) * GRID_ + (h[j][2] + HMAX);
        flat[1] = (NGRID3 - 1) - flat[0];   // inversion op is the exact mirror
        flat[2] = ((h[j][1] + HMAX) * GRID_ + (h[j][0] + HMAX)) * GRID_ + (HMAX - h[j][2]);
#pragma unroll
        for (int op = 0; op < 3; op++) {
            if (USELOHI) {
                int f = flat[op];
                int lo = (int)lo16[f];
                int hi = (int)((hi2[f >> 4] >> ((f & 15) * 2)) & 3u);
                r[op][j] = lo | (hi << 16);
            } else {
                r[op][j] = asu[flat[op]];
            }
        }
    }

    float s0 = eb[0], s1 = eb[1];
    float acc[3] = {0.f, 0.f, 0.f};
    if (USEZ) {
        const f4* Zp = (const f4*)ZS;
        // op-OUTER, c-inner: rows consumed completely while hot; NT (evict-first)
        // so the random ZS stream doesn't evict the L2-resident lo16/hi2 tables.
#pragma unroll
        for (int op = 0; op < 3; op++) {
            const f4* pa = Zp + (size_t)r[op][0] * 8;
            const f4* pb = Zp + (size_t)r[op][1] * 8;
            float a3 = 0.f;
#pragma unroll
            for (int c = 0; c < 8; c++) {
                f4 a = NTL(pa + c);
                f4 b = NTL(pb + c);
                float t;
                t = (fmaf(b.x, s1, a.x * s0) - Iv) * inv; a3 = fmaf(t, t, a3);
                t = (fmaf(b.y, s1, a.y * s0) - Iv) * inv; a3 = fmaf(t, t, a3);
                t = (fmaf(b.z, s1, a.z * s0) - Iv) * inv; a3 = fmaf(t, t, a3);
                t = (fmaf(b.w, s1, a.w * s0) - Iv) * inv; a3 = fmaf(t, t, a3);
            }
            acc[op] = a3;
        }
    } else {
        // fallback: gather qloc/Qs, recompute per-row scale inline
#pragma unroll
        for (int op = 0; op < 3; op++) {
            float q0a = qloc[r[op][0]], q1a = Qs[r[op][0]];
            float q0b = qloc[r[op][1]], q1b = Qs[r[op][1]];
            float sa = s0 * expf(fmaf(w[0], q0a, w[1] * q1a));
            float sb2 = s1 * expf(fmaf(w[0], q0b, w[1] * q1b));
            float a3 = 0.f;
            for (int mc = 0; mc < MC; mc++) {
                const float* ep = eps + (size_t)mc * RASU;
                float z0 = fmaf(q1a, ep[r[op][0]], q0a);
                float z1 = fmaf(q1b, ep[r[op][1]], q0b);
                float t = (fmaf(z1, sb2, z0 * sa) - Iv) * inv;
                a3 = fmaf(t, t, a3);
            }
            acc[op] = a3;
        }
    }

    double base_ll = -32.0 * ((double)logs + 0.5 * LOG2PI_D);
    int pidx = (int)(blockIdx.x & (NPART - 1));
    double* pp = partial + ((size_t)pidx * N_IMAGES + img) * 3;
#pragma unroll
    for (int op = 0; op < 3; op++) {
        double ll = -0.5 * (double)acc[op] + base_ll;
        atomicAdd(pp + op, ll);
    }
}

// ---- Kernel D: per-image reduce over partials, argmax -------------------------------
__global__ __launch_bounds__(256)
void img_kernel(const double* __restrict__ partial, double* __restrict__ accums,
                float* __restrict__ out)
{
    int i = blockIdx.x * 256 + threadIdx.x;
    if (i >= N_IMAGES) return;
    double l0 = 0, l1 = 0, l2 = 0;
    for (int p = 0; p < NPART; p++) {
        const double* q = partial + ((size_t)p * N_IMAGES + i) * 3;
        l0 += q[0]; l1 += q[1]; l2 += q[2];
    }
    const double ninv = 1.0 / (double)(MC * MC);
    l0 *= ninv; l1 *= ninv; l2 *= ninv;
    int idx = 0; double best = l0;
    if (l1 > best) { best = l1; idx = 1; }
    if (l2 > best) { best = l2; idx = 2; }
    out[1 + i] = (float)idx;
    atomicAdd(&accums[1], best);
}

// ---- Kernel E: final ELBO -----------------------------------------------------------
__global__ void final_kernel(const double* __restrict__ accums, float* __restrict__ out)
{
    double elbo = -(accums[1] / (double)N_IMAGES) + (accums[0] / (double)RASU);
    out[0] = (float)elbo;
}

extern "C" void kernel_launch(void* const* d_in, const int* in_sizes, int n_in,
                              void* d_out, int out_size, void* d_ws, size_t ws_size,
                              hipStream_t stream)
{
    const int*   hkl      = (const int*)  d_in[0];
    const float* I        = (const float*)d_in[1];
    const float* SigI     = (const float*)d_in[2];
    const int*   image_id = (const int*)  d_in[3];
    const float* metadata = (const float*)d_in[4];
    // d_in[5] harmonic_id: structurally arange//2, unused
    const int*   asu      = (const int*)  d_in[6];
    const float* qloc     = (const float*)d_in[7];
    const float* qraw     = (const float*)d_in[8];
    const float* eps      = (const float*)d_in[9];
    const float* sw       = (const float*)d_in[10];
    const float* sb       = (const float*)d_in[11];
    const float* ibias    = (const float*)d_in[12];
    float* out = (float*)d_out;

    char* ws = (char*)d_ws;
    size_t off = 0;
    double* partial = (double*)(ws + off); off += (size_t)NPART * N_IMAGES * 3 * sizeof(double);
    double* accums  = (double*)(ws + off); off += 2 * sizeof(double);
    off = (off + 15) & ~(size_t)15;
    float*  Qs      = (float*) (ws + off); off += (size_t)RASU * sizeof(float);
    unsigned int* lo16w = (unsigned int*)(ws + off); off += (size_t)NPAIRS * sizeof(unsigned int);
    unsigned int* hi2   = (unsigned int*)(ws + off); off += (size_t)((NPAIRS + 7) / 8) * sizeof(unsigned int);
    int useLoHi = (off <= ws_size) ? 1 : 0;
    off = (off + 127) & ~(size_t)127;
    float* ZS = (float*)(ws + off);
    size_t zbytes = (size_t)RASU * MC * sizeof(float);
    int useZ = (off + zbytes <= ws_size) ? 1 : 0;

    // partial + accums zeroing is folded into repack_kernel (grid-stride f4 stores)
    int zero_count = (int)((NPART * N_IMAGES * 3 * sizeof(double) + 2 * sizeof(double) + 15) / 16);
    int repackBlocks = (NPAIRS + 255) / 256;
    if (useLoHi) {
        repack_kernel<<<repackBlocks, 256, 0, stream>>>(asu, lo16w, hi2, (f4*)partial, zero_count);
    } else {
        (void)hipMemsetAsync(partial, 0, (size_t)zero_count * 16, stream);
    }

    prep_kernel<<<(RASU + 255) / 256, 256, 0, stream>>>(qloc, qraw, eps, sw, Qs, ZS, accums, useZ);

    int blocksC = (N_OBS + 255) / 256;
    const unsigned short* lo16 = (const unsigned short*)lo16w;
    if (useZ && useLoHi)
        obs_kernel<1,1><<<blocksC, 256, 0, stream>>>(hkl, I, SigI, image_id, metadata, asu, lo16, hi2,
                                                     qloc, Qs, ZS, eps, sw, sb, ibias, partial);
    else if (useZ)
        obs_kernel<1,0><<<blocksC, 256, 0, stream>>>(hkl, I, SigI, image_id, metadata, asu, lo16, hi2,
                                                     qloc, Qs, ZS, eps, sw, sb, ibias, partial);
    else if (useLoHi)
        obs_kernel<0,1><<<blocksC, 256, 0, stream>>>(hkl, I, SigI, image_id, metadata, asu, lo16, hi2,
                                                     qloc, Qs, ZS, eps, sw, sb, ibias, partial);
    else
        obs_kernel<0,0><<<blocksC, 256, 0, stream>>>(hkl, I, SigI, image_id, metadata, asu, lo16, hi2,
                                                     qloc, Qs, ZS, eps, sw, sb, ibias, partial);

    img_kernel<<<(N_IMAGES + 255) / 256, 256, 0, stream>>>(partial, accums, out);
    final_kernel<<<1, 1, 0, stream>>>(accums, out);
}

// Round 7
// 466.798 us; speedup vs baseline: 1.7824x; 1.7824x over previous
//
#include <hip/hip_runtime.h>
#include <math.h>

#define N_PRED   2000000
#define N_OBS    1000000
#define RASU     200000
#define N_IMAGES 2000
#define HMAX     60
#define GRID_    121
#define NGRID3   1771561      // 121^3
#define NPAIRS   885781       // (NGRID3+1)/2
#define MC       32
#define NPART    64
#define LOG2PI_D 1.8378770664093453
#define PREP_PAD 33           // stride ≡ 1 (mod 32): conflict-free LDS transpose

// Clang-native vector types: __builtin_nontemporal_load/store require these
typedef float f4 __attribute__((ext_vector_type(4)));
typedef float f2 __attribute__((ext_vector_type(2)));
typedef int   i2 __attribute__((ext_vector_type(2)));

#define NTL(p) __builtin_nontemporal_load(p)   // ONLY for single-touch streams

// ---- Kernel A0: repack asu into packed-lo16 u32 + 2-bit hi words; zero partial+accums
__global__ __launch_bounds__(256)
void repack_kernel(const int* __restrict__ asu, unsigned int* __restrict__ lo16w,
                   unsigned int* __restrict__ hi2, f4* __restrict__ zero_base,
                   int zero_count)
{
    __shared__ unsigned int hbits[256];
    int j = blockIdx.x * 256 + threadIdx.x;   // pair index (entries 2j, 2j+1)
    unsigned int myh = 0;
    if (j < NPAIRS) {
        int i0 = 2 * j;
        i2 a;
        if (i0 + 1 < NGRID3) a = *(const i2*)(asu + i0);
        else { a.x = asu[i0]; a.y = 0; }
        lo16w[j] = ((unsigned int)a.x & 0xFFFFu) | (((unsigned int)a.y & 0xFFFFu) << 16);
        myh = (((unsigned int)a.x >> 16) & 3u) | ((((unsigned int)a.y >> 16) & 3u) << 2);
    }
    hbits[threadIdx.x] = myh;
    __syncthreads();
    if ((threadIdx.x & 7) == 0 && j < NPAIRS) {
        unsigned int wbits = 0;
#pragma unroll
        for (int k = 0; k < 8; k++) wbits |= hbits[threadIdx.x + k] << (4 * k);
        hi2[j >> 3] = wbits;
    }
    // grid-stride zero of partial bins + accums (16B chunks)
    f4 zero = {0.f, 0.f, 0.f, 0.f};
    for (int k = j; k < zero_count; k += gridDim.x * 256) zero_base[k] = zero;
}

// ---- Kernel A: softplus; ZS[r][mc] = exp(w0*ql+w1*qs) * (ql + qs*eps[mc][r]); KL ----
__global__ __launch_bounds__(256)
void prep_kernel(const float* __restrict__ qloc, const float* __restrict__ qraw,
                 const float* __restrict__ eps, const float* __restrict__ sw,
                 float* __restrict__ Qs, float* __restrict__ ZS,
                 double* __restrict__ accums, int useZ)
{
    __shared__ float lds[256 * PREP_PAD];
    int t = threadIdx.x;
    int base = blockIdx.x * 256;
    int r = base + t;
    bool valid = (r < RASU);
    double klv = 0.0;
    float qs = 1.f, ql = 0.f, ewq = 0.f;
    if (valid) {
        float x  = qraw[r];
        float sp = (x > 0.f) ? (x + log1pf(expf(-x))) : log1pf(expf(x));
        qs = sp + 1e-6f;
        ql = qloc[r];
        Qs[r] = qs;
        ewq = expf(fmaf(sw[0], ql, sw[1] * qs));
        klv = (double)(-logf(qs) + 0.5f * (qs * qs + ql * ql) - 0.5f);
    }
#pragma unroll
    for (int off = 32; off; off >>= 1) klv += __shfl_down(klv, off);
    if ((t & 63) == 0) atomicAdd(&accums[0], klv);

    if (useZ) {
        // load phase: 32 coalesced column reads, scale, into LDS row t
#pragma unroll 8
        for (int k = 0; k < MC; k++) {
            float v = valid ? fmaf(qs, eps[(size_t)k * RASU + r], ql) * ewq : 0.f;
            lds[t * PREP_PAD + k] = v;
        }
        __syncthreads();
        // store phase: lanes cover (row, col16B) so each wave writes 1KB contiguous
        int rr0 = t >> 3, cc = t & 7;
        f4* Zp = (f4*)ZS;
#pragma unroll
        for (int i = 0; i < 8; i++) {
            int rr  = rr0 + i * 32;
            int row = base + rr;
            const float* p = &lds[rr * PREP_PAD + cc * 4];
            f4 v = {p[0], p[1], p[2], p[3]};
            if (row < RASU) Zp[(size_t)row * 8 + cc] = v;
        }
    }
}

// ---- Kernel C: one thread per observation ------------------------------------------
template <int USEZ, int USELOHI>
__global__ __launch_bounds__(256)
void obs_kernel(const int* __restrict__ hkl, const float* __restrict__ I,
                const float* __restrict__ SigI, const int* __restrict__ image_id,
                const float* __restrict__ metadata, const int* __restrict__ asu,
                const unsigned short* __restrict__ lo16, const unsigned int* __restrict__ hi2,
                const float* __restrict__ qloc, const float* __restrict__ Qs,
                const float* __restrict__ ZS, const float* __restrict__ eps,
                const float* __restrict__ sw, const float* __restrict__ sbp,
                const float* __restrict__ ibias, double* __restrict__ partial)
{
    int o = blockIdx.x * 256 + threadIdx.x;
    if (o >= N_OBS) return;

    float w[9];
#pragma unroll
    for (int j = 0; j < 9; j++) w[j] = sw[j];
    float sb = sbp[0];

    float Iv = NTL(I + o), Sv = NTL(SigI + o);
    float inv  = 1.0f / Sv;
    float logs = logf(Sv);

    int p0 = 2 * o;
    i2 ia = NTL((const i2*)(image_id + p0));
    int img = ia.y;  // numpy last-write-wins scatter: pred 2o+1 wins

    // per-prediction base of the log-scale (op-independent); eb = exp(base)
    float eb[2];
    {
        const f2* m0 = (const f2*)(metadata + (size_t)p0 * 5);
        f2 ma = NTL(m0), mb = NTL(m0 + 1), mc_ = NTL(m0 + 2), md = NTL(m0 + 3), me = NTL(m0 + 4);
        float m[10] = {ma.x, ma.y, mb.x, mb.y, mc_.x, mc_.y, md.x, md.y, me.x, me.y};
#pragma unroll
        for (int j = 0; j < 2; j++) {
            float b = w[2] * Iv;
            b = fmaf(w[3], Sv, b);
#pragma unroll
            for (int k = 0; k < 5; k++) b = fmaf(w[4 + k], m[5 * j + k], b);
            eb[j] = expf(b + sb + ibias[j == 0 ? ia.x : ia.y]);
        }
    }

    int h[2][3];
    {
        const i2* hp = (const i2*)(hkl + (size_t)p0 * 3);
        i2 h01 = NTL(hp), h23 = NTL(hp + 1), h45 = NTL(hp + 2);
        h[0][0] = h01.x; h[0][1] = h01.y; h[0][2] = h23.x;
        h[1][0] = h23.y; h[1][1] = h45.x; h[1][2] = h45.y;
    }

    int r[3][2];
#pragma unroll
    for (int j = 0; j < 2; j++) {
        int flat[3];
        flat[0] = ((h[j][0] + HMAX) * GRID_ + (h[j][1] + HMAX)) * GRID_ + (h[j][2] + HMAX);
        flat[1] = (NGRID3 - 1) - flat[0];   // inversion op is the exact mirror
        flat[2] = ((h[j][1] + HMAX) * GRID_ + (h[j][0] + HMAX)) * GRID_ + (HMAX - h[j][2]);
#pragma unroll
        for (int op = 0; op < 3; op++) {
            if (USELOHI) {
                int f = flat[op];
                int lo = (int)lo16[f];
                int hi = (int)((hi2[f >> 4] >> ((f & 15) * 2)) & 3u);
                r[op][j] = lo | (hi << 16);
            } else {
                r[op][j] = asu[flat[op]];
            }
        }
    }

    float s0 = eb[0], s1 = eb[1];
    float acc[3] = {0.f, 0.f, 0.f};
    if (USEZ) {
        const f4* Zp = (const f4*)ZS;
        // op-OUTER, c-inner: rows consumed completely while hot. CACHED loads:
        // ZS rows have ~30x cross-thread reuse -> L2/L3 must retain them (NT
        // loads here cost +0.35GB fetch and -0.8TB/s BW, measured R6).
#pragma unroll
        for (int op = 0; op < 3; op++) {
            const f4* pa = Zp + (size_t)r[op][0] * 8;
            const f4* pb = Zp + (size_t)r[op][1] * 8;
            float a3 = 0.f;
#pragma unroll
            for (int c = 0; c < 8; c++) {
                f4 a = pa[c];
                f4 b = pb[c];
                float t;
                t = (fmaf(b.x, s1, a.x * s0) - Iv) * inv; a3 = fmaf(t, t, a3);
                t = (fmaf(b.y, s1, a.y * s0) - Iv) * inv; a3 = fmaf(t, t, a3);
                t = (fmaf(b.z, s1, a.z * s0) - Iv) * inv; a3 = fmaf(t, t, a3);
                t = (fmaf(b.w, s1, a.w * s0) - Iv) * inv; a3 = fmaf(t, t, a3);
            }
            acc[op] = a3;
        }
    } else {
        // fallback: gather qloc/Qs, recompute per-row scale inline
#pragma unroll
        for (int op = 0; op < 3; op++) {
            float q0a = qloc[r[op][0]], q1a = Qs[r[op][0]];
            float q0b = qloc[r[op][1]], q1b = Qs[r[op][1]];
            float sa = s0 * expf(fmaf(w[0], q0a, w[1] * q1a));
            float sb2 = s1 * expf(fmaf(w[0], q0b, w[1] * q1b));
            float a3 = 0.f;
            for (int mc = 0; mc < MC; mc++) {
                const float* ep = eps + (size_t)mc * RASU;
                float z0 = fmaf(q1a, ep[r[op][0]], q0a);
                float z1 = fmaf(q1b, ep[r[op][1]], q0b);
                float t = (fmaf(z1, sb2, z0 * sa) - Iv) * inv;
                a3 = fmaf(t, t, a3);
            }
            acc[op] = a3;
        }
    }

    double base_ll = -32.0 * ((double)logs + 0.5 * LOG2PI_D);
    int pidx = (int)(blockIdx.x & (NPART - 1));
    double* pp = partial + ((size_t)pidx * N_IMAGES + img) * 3;
#pragma unroll
    for (int op = 0; op < 3; op++) {
        double ll = -0.5 * (double)acc[op] + base_ll;
        atomicAdd(pp + op, ll);
    }
}

// ---- Kernel D: per-image reduce over partials, argmax -------------------------------
__global__ __launch_bounds__(256)
void img_kernel(const double* __restrict__ partial, double* __restrict__ accums,
                float* __restrict__ out)
{
    int i = blockIdx.x * 256 + threadIdx.x;
    if (i >= N_IMAGES) return;
    double l0 = 0, l1 = 0, l2 = 0;
    for (int p = 0; p < NPART; p++) {
        const double* q = partial + ((size_t)p * N_IMAGES + i) * 3;
        l0 += q[0]; l1 += q[1]; l2 += q[2];
    }
    const double ninv = 1.0 / (double)(MC * MC);
    l0 *= ninv; l1 *= ninv; l2 *= ninv;
    int idx = 0; double best = l0;
    if (l1 > best) { best = l1; idx = 1; }
    if (l2 > best) { best = l2; idx = 2; }
    out[1 + i] = (float)idx;
    atomicAdd(&accums[1], best);
}

// ---- Kernel E: final ELBO -----------------------------------------------------------
__global__ void final_kernel(const double* __restrict__ accums, float* __restrict__ out)
{
    double elbo = -(accums[1] / (double)N_IMAGES) + (accums[0] / (double)RASU);
    out[0] = (float)elbo;
}

extern "C" void kernel_launch(void* const* d_in, const int* in_sizes, int n_in,
                              void* d_out, int out_size, void* d_ws, size_t ws_size,
                              hipStream_t stream)
{
    const int*   hkl      = (const int*)  d_in[0];
    const float* I        = (const float*)d_in[1];
    const float* SigI     = (const float*)d_in[2];
    const int*   image_id = (const int*)  d_in[3];
    const float* metadata = (const float*)d_in[4];
    // d_in[5] harmonic_id: structurally arange//2, unused
    const int*   asu      = (const int*)  d_in[6];
    const float* qloc     = (const float*)d_in[7];
    const float* qraw     = (const float*)d_in[8];
    const float* eps      = (const float*)d_in[9];
    const float* sw       = (const float*)d_in[10];
    const float* sb       = (const float*)d_in[11];
    const float* ibias    = (const float*)d_in[12];
    float* out = (float*)d_out;

    char* ws = (char*)d_ws;
    size_t off = 0;
    double* partial = (double*)(ws + off); off += (size_t)NPART * N_IMAGES * 3 * sizeof(double);
    double* accums  = (double*)(ws + off); off += 2 * sizeof(double);
    off = (off + 15) & ~(size_t)15;
    float*  Qs      = (float*) (ws + off); off += (size_t)RASU * sizeof(float);
    unsigned int* lo16w = (unsigned int*)(ws + off); off += (size_t)NPAIRS * sizeof(unsigned int);
    unsigned int* hi2   = (unsigned int*)(ws + off); off += (size_t)((NPAIRS + 7) / 8) * sizeof(unsigned int);
    int useLoHi = (off <= ws_size) ? 1 : 0;
    off = (off + 127) & ~(size_t)127;
    float* ZS = (float*)(ws + off);
    size_t zbytes = (size_t)RASU * MC * sizeof(float);
    int useZ = (off + zbytes <= ws_size) ? 1 : 0;

    // partial + accums zeroing is folded into repack_kernel (grid-stride f4 stores)
    int zero_count = (int)((NPART * N_IMAGES * 3 * sizeof(double) + 2 * sizeof(double) + 15) / 16);
    int repackBlocks = (NPAIRS + 255) / 256;
    if (useLoHi) {
        repack_kernel<<<repackBlocks, 256, 0, stream>>>(asu, lo16w, hi2, (f4*)partial, zero_count);
    } else {
        (void)hipMemsetAsync(partial, 0, (size_t)zero_count * 16, stream);
    }

    prep_kernel<<<(RASU + 255) / 256, 256, 0, stream>>>(qloc, qraw, eps, sw, Qs, ZS, accums, useZ);

    int blocksC = (N_OBS + 255) / 256;
    const unsigned short* lo16 = (const unsigned short*)lo16w;
    if (useZ && useLoHi)
        obs_kernel<1,1><<<blocksC, 256, 0, stream>>>(hkl, I, SigI, image_id, metadata, asu, lo16, hi2,
                                                     qloc, Qs, ZS, eps, sw, sb, ibias, partial);
    else if (useZ)
        obs_kernel<1,0><<<blocksC, 256, 0, stream>>>(hkl, I, SigI, image_id, metadata, asu, lo16, hi2,
                                                     qloc, Qs, ZS, eps, sw, sb, ibias, partial);
    else if (useLoHi)
        obs_kernel<0,1><<<blocksC, 256, 0, stream>>>(hkl, I, SigI, image_id, metadata, asu, lo16, hi2,
                                                     qloc, Qs, ZS, eps, sw, sb, ibias, partial);
    else
        obs_kernel<0,0><<<blocksC, 256, 0, stream>>>(hkl, I, SigI, image_id, metadata, asu, lo16, hi2,
                                                     qloc, Qs, ZS, eps, sw, sb, ibias, partial);

    img_kernel<<<(N_IMAGES + 255) / 256, 256, 0, stream>>>(partial, accums, out);
    final_kernel<<<1, 1, 0, stream>>>(accums, out);
}

// Round 8
// 394.237 us; speedup vs baseline: 2.1104x; 1.1841x over previous
//
#include <hip/hip_runtime.h>
#include <math.h>

#define N_PRED   2000000
#define N_OBS    1000000
#define RASU     200000
#define N_IMAGES 2000
#define HMAX     60
#define GRID_    121
#define NGRID3   1771561      // 121^3
#define NPAIRS   885781       // (NGRID3+1)/2
#define MC       32
#define NPART    64
#define LOG2PI_D 1.8378770664093453
#define PREP_PAD 33           // stride ≡ 1 (mod 32): conflict-free LDS transpose

// Clang-native vector types: __builtin_nontemporal_load/store require these
typedef float f4 __attribute__((ext_vector_type(4)));
typedef float f2 __attribute__((ext_vector_type(2)));
typedef int   i2 __attribute__((ext_vector_type(2)));

#define NTL(p) __builtin_nontemporal_load(p)   // ONLY for single-touch streams

// ---- Kernel A0: repack asu into packed-lo16 u32 + 2-bit hi words; zero partial+accums
__global__ __launch_bounds__(256)
void repack_kernel(const int* __restrict__ asu, unsigned int* __restrict__ lo16w,
                   unsigned int* __restrict__ hi2, f4* __restrict__ zero_base,
                   int zero_count)
{
    __shared__ unsigned int hbits[256];
    int j = blockIdx.x * 256 + threadIdx.x;   // pair index (entries 2j, 2j+1)
    unsigned int myh = 0;
    if (j < NPAIRS) {
        int i0 = 2 * j;
        i2 a;
        if (i0 + 1 < NGRID3) a = *(const i2*)(asu + i0);
        else { a.x = asu[i0]; a.y = 0; }
        lo16w[j] = ((unsigned int)a.x & 0xFFFFu) | (((unsigned int)a.y & 0xFFFFu) << 16);
        myh = (((unsigned int)a.x >> 16) & 3u) | ((((unsigned int)a.y >> 16) & 3u) << 2);
    }
    hbits[threadIdx.x] = myh;
    __syncthreads();
    if ((threadIdx.x & 7) == 0 && j < NPAIRS) {
        unsigned int wbits = 0;
#pragma unroll
        for (int k = 0; k < 8; k++) wbits |= hbits[threadIdx.x + k] << (4 * k);
        hi2[j >> 3] = wbits;
    }
    // grid-stride zero of partial bins + accums (16B chunks)
    f4 zero = {0.f, 0.f, 0.f, 0.f};
    for (int k = j; k < zero_count; k += gridDim.x * 256) zero_base[k] = zero;
}

// ---- Kernel A: softplus; ZS[r][mc] = exp(w0*ql+w1*qs) * (ql + qs*eps[mc][r]); KL ----
__global__ __launch_bounds__(256)
void prep_kernel(const float* __restrict__ qloc, const float* __restrict__ qraw,
                 const float* __restrict__ eps, const float* __restrict__ sw,
                 float* __restrict__ Qs, float* __restrict__ ZS,
                 double* __restrict__ accums, int useZ)
{
    __shared__ float lds[256 * PREP_PAD];
    int t = threadIdx.x;
    int base = blockIdx.x * 256;
    int r = base + t;
    bool valid = (r < RASU);
    double klv = 0.0;
    float qs = 1.f, ql = 0.f, ewq = 0.f;
    if (valid) {
        float x  = qraw[r];
        float sp = (x > 0.f) ? (x + log1pf(expf(-x))) : log1pf(expf(x));
        qs = sp + 1e-6f;
        ql = qloc[r];
        Qs[r] = qs;
        ewq = expf(fmaf(sw[0], ql, sw[1] * qs));
        klv = (double)(-logf(qs) + 0.5f * (qs * qs + ql * ql) - 0.5f);
    }
#pragma unroll
    for (int off = 32; off; off >>= 1) klv += __shfl_down(klv, off);
    if ((t & 63) == 0) atomicAdd(&accums[0], klv);

    if (useZ) {
        // load phase: 32 coalesced column reads, scale, into LDS row t
#pragma unroll 8
        for (int k = 0; k < MC; k++) {
            float v = valid ? fmaf(qs, eps[(size_t)k * RASU + r], ql) * ewq : 0.f;
            lds[t * PREP_PAD + k] = v;
        }
        __syncthreads();
        // store phase: lanes cover (row, col16B) so each wave writes 1KB contiguous
        int rr0 = t >> 3, cc = t & 7;
        f4* Zp = (f4*)ZS;
#pragma unroll
        for (int i = 0; i < 8; i++) {
            int rr  = rr0 + i * 32;
            int row = base + rr;
            const float* p = &lds[rr * PREP_PAD + cc * 4];
            f4 v = {p[0], p[1], p[2], p[3]};
            if (row < RASU) Zp[(size_t)row * 8 + cc] = v;
        }
    }
}

// 4-term partial of sum((z0*s0+z1*s1 - I)*inv)^2, exact reference arithmetic order
__device__ __forceinline__ float tsum4(f4 a, f4 b, float s0, float s1, float Iv, float inv)
{
    float acc = 0.f, t;
    t = (fmaf(b.x, s1, a.x * s0) - Iv) * inv; acc = fmaf(t, t, acc);
    t = (fmaf(b.y, s1, a.y * s0) - Iv) * inv; acc = fmaf(t, t, acc);
    t = (fmaf(b.z, s1, a.z * s0) - Iv) * inv; acc = fmaf(t, t, acc);
    t = (fmaf(b.w, s1, a.w * s0) - Iv) * inv; acc = fmaf(t, t, acc);
    return acc;
}

// ---- Kernel C: phase 1 = 1 thread/obs scalar; phase 2 = 8 lanes/obs cooperative ----
template <int USEZ, int USELOHI>
__global__ __launch_bounds__(256)
void obs_kernel(const int* __restrict__ hkl, const float* __restrict__ I,
                const float* __restrict__ SigI, const int* __restrict__ image_id,
                const float* __restrict__ metadata, const int* __restrict__ asu,
                const unsigned short* __restrict__ lo16, const unsigned int* __restrict__ hi2,
                const float* __restrict__ qloc, const float* __restrict__ Qs,
                const float* __restrict__ ZS, const float* __restrict__ eps,
                const float* __restrict__ sw, const float* __restrict__ sbp,
                const float* __restrict__ ibias, double* __restrict__ partial)
{
    int tid  = threadIdx.x;
    int lane = tid & 63;
    int o = blockIdx.x * 256 + tid;
    bool valid = (o < N_OBS);

    float w[9];
#pragma unroll
    for (int j = 0; j < 9; j++) w[j] = sw[j];
    float sbv = sbp[0];

    // ---------------- phase 1: per-thread scalar work for OWN obs ----------------
    float Iv = 0.f, Sv = 1.f;
    int img = -1;
    float eb0 = 0.f, eb1 = 0.f;
    int r00 = 0, r01 = 0, r10 = 0, r11 = 0, r20 = 0, r21 = 0;

    if (valid) {
        Iv = NTL(I + o); Sv = NTL(SigI + o);
        int p0 = 2 * o;
        i2 ia = NTL((const i2*)(image_id + p0));
        img = ia.y;  // numpy last-write-wins scatter: pred 2o+1 wins

        const f2* m0 = (const f2*)(metadata + (size_t)p0 * 5);
        f2 ma = NTL(m0), mb = NTL(m0 + 1), mc_ = NTL(m0 + 2), md = NTL(m0 + 3), me = NTL(m0 + 4);
        float m[10] = {ma.x, ma.y, mb.x, mb.y, mc_.x, mc_.y, md.x, md.y, me.x, me.y};
        float eb[2];
#pragma unroll
        for (int j = 0; j < 2; j++) {
            float b = w[2] * Iv;
            b = fmaf(w[3], Sv, b);
#pragma unroll
            for (int k = 0; k < 5; k++) b = fmaf(w[4 + k], m[5 * j + k], b);
            eb[j] = expf(b + sbv + ibias[j == 0 ? ia.x : ia.y]);
        }
        eb0 = eb[0]; eb1 = eb[1];

        int h[2][3];
        const i2* hp = (const i2*)(hkl + (size_t)p0 * 3);
        i2 h01 = NTL(hp), h23 = NTL(hp + 1), h45 = NTL(hp + 2);
        h[0][0] = h01.x; h[0][1] = h01.y; h[0][2] = h23.x;
        h[1][0] = h23.y; h[1][1] = h45.x; h[1][2] = h45.y;

        int r[3][2];
#pragma unroll
        for (int j = 0; j < 2; j++) {
            int flat[3];
            flat[0] = ((h[j][0] + HMAX) * GRID_ + (h[j][1] + HMAX)) * GRID_ + (h[j][2] + HMAX);
            flat[1] = (NGRID3 - 1) - flat[0];   // inversion op is the exact mirror
            flat[2] = ((h[j][1] + HMAX) * GRID_ + (h[j][0] + HMAX)) * GRID_ + (HMAX - h[j][2]);
#pragma unroll
            for (int op = 0; op < 3; op++) {
                if (USELOHI) {
                    int f = flat[op];
                    int lo = (int)lo16[f];
                    int hi = (int)((hi2[f >> 4] >> ((f & 15) * 2)) & 3u);
                    r[op][j] = lo | (hi << 16);
                } else {
                    r[op][j] = asu[flat[op]];
                }
            }
        }
        r00 = r[0][0]; r01 = r[0][1];
        r10 = r[1][0]; r11 = r[1][1];
        r20 = r[2][0]; r21 = r[2][1];
    }

    float inv  = 1.0f / Sv;
    float logs = logf(Sv);
    int pidx = (int)(blockIdx.x & (NPART - 1));

    if (USEZ) {
        // ------------- phase 2: 8-lane groups, coalesced 128B row loads -------------
        const f4* Zp = (const f4*)ZS;
        int grp = lane >> 3, sub = lane & 7;
#pragma unroll
        for (int i = 0; i < 8; i++) {
            int L = i * 8 + grp;                  // owner lane within this wave
            int   im = __shfl(img, L, 64);
            int  q00 = __shfl(r00, L, 64), q01 = __shfl(r01, L, 64);
            int  q10 = __shfl(r10, L, 64), q11 = __shfl(r11, L, 64);
            int  q20 = __shfl(r20, L, 64), q21 = __shfl(r21, L, 64);
            float S0 = __shfl(eb0, L, 64), S1 = __shfl(eb1, L, 64);
            float CI = __shfl(Iv,  L, 64), CV = __shfl(inv, L, 64);
            float LG = __shfl(logs, L, 64);
            if (im >= 0) {                        // group-uniform predicate
                f4 A0 = Zp[(size_t)q00 * 8 + sub], B0 = Zp[(size_t)q01 * 8 + sub];
                f4 A1 = Zp[(size_t)q10 * 8 + sub], B1 = Zp[(size_t)q11 * 8 + sub];
                f4 A2 = Zp[(size_t)q20 * 8 + sub], B2 = Zp[(size_t)q21 * 8 + sub];
                float a0 = tsum4(A0, B0, S0, S1, CI, CV);
                float a1 = tsum4(A1, B1, S0, S1, CI, CV);
                float a2 = tsum4(A2, B2, S0, S1, CI, CV);
                // 8-lane tree reduce (masks 1,2,4 stay within the group)
#pragma unroll
                for (int msk = 1; msk <= 4; msk <<= 1) {
                    a0 += __shfl_xor(a0, msk, 64);
                    a1 += __shfl_xor(a1, msk, 64);
                    a2 += __shfl_xor(a2, msk, 64);
                }
                if (sub == 0) {
                    double base_ll = -32.0 * ((double)LG + 0.5 * LOG2PI_D);
                    double* pp = partial + ((size_t)pidx * N_IMAGES + im) * 3;
                    atomicAdd(pp + 0, -0.5 * (double)a0 + base_ll);
                    atomicAdd(pp + 1, -0.5 * (double)a1 + base_ll);
                    atomicAdd(pp + 2, -0.5 * (double)a2 + base_ll);
                }
            }
        }
    } else {
        // fallback: per-thread gather of qloc/Qs + eps columns
        if (!valid) return;
        int rr[3][2] = {{r00, r01}, {r10, r11}, {r20, r21}};
        float acc[3];
#pragma unroll
        for (int op = 0; op < 3; op++) {
            float q0a = qloc[rr[op][0]], q1a = Qs[rr[op][0]];
            float q0b = qloc[rr[op][1]], q1b = Qs[rr[op][1]];
            float sa  = eb0 * expf(fmaf(w[0], q0a, w[1] * q1a));
            float sb2 = eb1 * expf(fmaf(w[0], q0b, w[1] * q1b));
            float a3 = 0.f;
            for (int mc = 0; mc < MC; mc++) {
                const float* ep = eps + (size_t)mc * RASU;
                float z0 = fmaf(q1a, ep[rr[op][0]], q0a);
                float z1 = fmaf(q1b, ep[rr[op][1]], q0b);
                float t = (fmaf(z1, sb2, z0 * sa) - Iv) * inv;
                a3 = fmaf(t, t, a3);
            }
            acc[op] = a3;
        }
        double base_ll = -32.0 * ((double)logs + 0.5 * LOG2PI_D);
        double* pp = partial + ((size_t)pidx * N_IMAGES + img) * 3;
#pragma unroll
        for (int op = 0; op < 3; op++)
            atomicAdd(pp + op, -0.5 * (double)acc[op] + base_ll);
    }
}

// ---- Kernel D: per-image reduce over partials, argmax -------------------------------
__global__ __launch_bounds__(256)
void img_kernel(const double* __restrict__ partial, double* __restrict__ accums,
                float* __restrict__ out)
{
    int i = blockIdx.x * 256 + threadIdx.x;
    if (i >= N_IMAGES) return;
    double l0 = 0, l1 = 0, l2 = 0;
    for (int p = 0; p < NPART; p++) {
        const double* q = partial + ((size_t)p * N_IMAGES + i) * 3;
        l0 += q[0]; l1 += q[1]; l2 += q[2];
    }
    const double ninv = 1.0 / (double)(MC * MC);
    l0 *= ninv; l1 *= ninv; l2 *= ninv;
    int idx = 0; double best = l0;
    if (l1 > best) { best = l1; idx = 1; }
    if (l2 > best) { best = l2; idx = 2; }
    out[1 + i] = (float)idx;
    atomicAdd(&accums[1], best);
}

// ---- Kernel E: final ELBO -----------------------------------------------------------
__global__ void final_kernel(const double* __restrict__ accums, float* __restrict__ out)
{
    double elbo = -(accums[1] / (double)N_IMAGES) + (accums[0] / (double)RASU);
    out[0] = (float)elbo;
}

extern "C" void kernel_launch(void* const* d_in, const int* in_sizes, int n_in,
                              void* d_out, int out_size, void* d_ws, size_t ws_size,
                              hipStream_t stream)
{
    const int*   hkl      = (const int*)  d_in[0];
    const float* I        = (const float*)d_in[1];
    const float* SigI     = (const float*)d_in[2];
    const int*   image_id = (const int*)  d_in[3];
    const float* metadata = (const float*)d_in[4];
    // d_in[5] harmonic_id: structurally arange//2, unused
    const int*   asu      = (const int*)  d_in[6];
    const float* qloc     = (const float*)d_in[7];
    const float* qraw     = (const float*)d_in[8];
    const float* eps      = (const float*)d_in[9];
    const float* sw       = (const float*)d_in[10];
    const float* sb       = (const float*)d_in[11];
    const float* ibias    = (const float*)d_in[12];
    float* out = (float*)d_out;

    char* ws = (char*)d_ws;
    size_t off = 0;
    double* partial = (double*)(ws + off); off += (size_t)NPART * N_IMAGES * 3 * sizeof(double);
    double* accums  = (double*)(ws + off); off += 2 * sizeof(double);
    off = (off + 15) & ~(size_t)15;
    float*  Qs      = (float*) (ws + off); off += (size_t)RASU * sizeof(float);
    unsigned int* lo16w = (unsigned int*)(ws + off); off += (size_t)NPAIRS * sizeof(unsigned int);
    unsigned int* hi2   = (unsigned int*)(ws + off); off += (size_t)((NPAIRS + 7) / 8) * sizeof(unsigned int);
    int useLoHi = (off <= ws_size) ? 1 : 0;
    off = (off + 127) & ~(size_t)127;
    float* ZS = (float*)(ws + off);
    size_t zbytes = (size_t)RASU * MC * sizeof(float);
    int useZ = (off + zbytes <= ws_size) ? 1 : 0;

    // partial + accums zeroing is folded into repack_kernel (grid-stride f4 stores)
    int zero_count = (int)((NPART * N_IMAGES * 3 * sizeof(double) + 2 * sizeof(double) + 15) / 16);
    int repackBlocks = (NPAIRS + 255) / 256;
    if (useLoHi) {
        repack_kernel<<<repackBlocks, 256, 0, stream>>>(asu, lo16w, hi2, (f4*)partial, zero_count);
    } else {
        (void)hipMemsetAsync(partial, 0, (size_t)zero_count * 16, stream);
    }

    prep_kernel<<<(RASU + 255) / 256, 256, 0, stream>>>(qloc, qraw, eps, sw, Qs, ZS, accums, useZ);

    int blocksC = (N_OBS + 255) / 256;
    const unsigned short* lo16 = (const unsigned short*)lo16w;
    if (useZ && useLoHi)
        obs_kernel<1,1><<<blocksC, 256, 0, stream>>>(hkl, I, SigI, image_id, metadata, asu, lo16, hi2,
                                                     qloc, Qs, ZS, eps, sw, sb, ibias, partial);
    else if (useZ)
        obs_kernel<1,0><<<blocksC, 256, 0, stream>>>(hkl, I, SigI, image_id, metadata, asu, lo16, hi2,
                                                     qloc, Qs, ZS, eps, sw, sb, ibias, partial);
    else if (useLoHi)
        obs_kernel<0,1><<<blocksC, 256, 0, stream>>>(hkl, I, SigI, image_id, metadata, asu, lo16, hi2,
                                                     qloc, Qs, ZS, eps, sw, sb, ibias, partial);
    else
        obs_kernel<0,0><<<blocksC, 256, 0, stream>>>(hkl, I, SigI, image_id, metadata, asu, lo16, hi2,
                                                     qloc, Qs, ZS, eps, sw, sb, ibias, partial);

    img_kernel<<<(N_IMAGES + 255) / 256, 256, 0, stream>>>(partial, accums, out);
    final_kernel<<<1, 1, 0, stream>>>(accums, out);
}